// Round 1
// baseline (500.446 us; speedup 1.0000x reference)
//
#include <hip/hip_runtime.h>

// Shifted 3x3 VALID conv: out[n][o][x][y] = bias[o] +
//   sum_{c,i,j} inp[n][c][wrap(x+i-1)][y+j] * filt[o][c][i][j]
// B=8, Cin=Cout=8, H=W=1024, OH=OW=1022, fp32.

#define H     1024
#define W     1024
#define OH    1022
#define OW    1022
#define CIN   8
#define COUT  8

#define TX    16            // output rows per block
#define TY    64            // output cols per block
#define ROWS  (TX + 2)      // 18 input rows staged
#define COLS  68            // 66 needed, padded to 68 for float4 staging
#define NCHK  (COLS / 4)    // 17 float4 chunks per row

__global__ __launch_bounds__(256, 4)
void conv_roll_kernel(const float* __restrict__ inp,
                      const float* __restrict__ filt,
                      const float* __restrict__ bias,
                      float* __restrict__ out) {
    __shared__ float s_in[CIN][ROWS][COLS];   // 8*18*68*4 = 38.25 KB -> 4 blocks/CU

    const int tid    = threadIdx.x;
    const int n      = blockIdx.z;
    const int x_base = blockIdx.y * TX;
    const int y_base = blockIdx.x * TY;

    // ---- Stage all 8 Cin tiles: float4 global loads -> LDS ----
    const float* __restrict__ inp_n = inp + ((size_t)n * CIN * H * W);
    for (int idx = tid; idx < CIN * ROWS * NCHK; idx += 256) {
        int c   = idx / (ROWS * NCHK);
        int rem = idx - c * (ROWS * NCHK);
        int r   = rem / NCHK;
        int col = (rem - r * NCHK) * 4;

        int gr = x_base + r - 1;                 // -1 .. 1024
        gr = (gr < 0) ? (H - 1) : ((gr > H - 1) ? (H - 1) : gr);  // -1 wraps (roll); 1024 clamps (dead)
        int gc = y_base + col;
        if (gc > W - 4) gc = W - 4;              // only chunks feeding out-of-range outputs clamp

        const float4 v = *(const float4*)(inp_n + (((size_t)c << 10) + gr) * W + gc);
        *(float4*)&s_in[c][r][col] = v;
    }
    __syncthreads();

    // ---- Compute: thread = (ty, tg): col y_base+ty, rows x_base + tg*4 + 0..3, all 8 couts ----
    const int ty = tid & 63;
    const int tg = tid >> 6;       // 0..3
    const int r0 = tg * 4;         // local input row base (tile row 0 == global row x_base-1)

    float acc[4][COUT];
#pragma unroll
    for (int o = 0; o < COUT; ++o) {
        const float bv = bias[o];                 // uniform -> s_load
#pragma unroll
        for (int u = 0; u < 4; ++u) acc[u][o] = bv;
    }

#pragma unroll 1
    for (int c = 0; c < CIN; ++c) {
        float in[6][3];
#pragma unroll
        for (int r = 0; r < 6; ++r)
#pragma unroll
            for (int j = 0; j < 3; ++j)
                in[r][j] = s_in[c][r0 + r][ty + j];

#pragma unroll
        for (int i = 0; i < 3; ++i)
#pragma unroll
            for (int j = 0; j < 3; ++j)
#pragma unroll
                for (int o = 0; o < COUT; ++o) {
                    const float fv = filt[((o * CIN + c) * 3 + i) * 3 + j];  // uniform -> s_load
#pragma unroll
                    for (int u = 0; u < 4; ++u)
                        acc[u][o] += in[u + i][j] * fv;
                }
    }

    // ---- Store ----
    const int yc = y_base + ty;
    if (yc < OW) {
#pragma unroll
        for (int u = 0; u < 4; ++u) {
            const int xr = x_base + r0 + u;
            if (xr < OH) {
#pragma unroll
                for (int o = 0; o < COUT; ++o) {
                    out[(((size_t)(n * COUT + o)) * OH + xr) * OW + yc] = acc[u][o];
                }
            }
        }
    }
}

extern "C" void kernel_launch(void* const* d_in, const int* in_sizes, int n_in,
                              void* d_out, int out_size, void* d_ws, size_t ws_size,
                              hipStream_t stream) {
    const float* inp  = (const float*)d_in[0];
    const float* filt = (const float*)d_in[1];
    const float* bias = (const float*)d_in[2];
    float* out = (float*)d_out;

    dim3 grid((OW + TY - 1) / TY,   // 16 y-tiles
              (OH + TX - 1) / TX,   // 64 x-tiles
              8);                   // batch
    conv_roll_kernel<<<grid, dim3(256), 0, stream>>>(inp, filt, bias, out);
}

// Round 2
// 494.154 us; speedup vs baseline: 1.0127x; 1.0127x over previous
//
#include <hip/hip_runtime.h>

// Shifted 3x3 VALID conv: out[n][o][x][y] = bias[o] +
//   sum_{c,i,j} inp[n][c][wrap(x+i-1)][y+j] * filt[o][c][i][j]
// B=8, Cin=Cout=8, H=W=1024, OH=OW=1022, fp32.
//
// R2: 512 threads/block (2 rows/thread) at unchanged 38.25 KB LDS ->
// 4 blocks/CU x 8 waves = 32 waves/CU (was 16). Occupancy was the limiter
// (VALUBusy 47%, HBM 32%, Occ 42% - classic latency-bound signature).

#define H     1024
#define W     1024
#define OH    1022
#define OW    1022
#define CIN   8
#define COUT  8

#define TX    16            // output rows per block
#define TY    64            // output cols per block
#define ROWS  (TX + 2)      // 18 input rows staged
#define COLS  68            // 66 needed, padded to 68 for float4 staging
#define NCHK  (COLS / 4)    // 17 float4 chunks per row
#define NTHREADS 512
#define RPT   2             // output rows per thread

__global__ __launch_bounds__(NTHREADS, 8)
void conv_roll_kernel(const float* __restrict__ inp,
                      const float* __restrict__ filt,
                      const float* __restrict__ bias,
                      float* __restrict__ out) {
    __shared__ float s_in[CIN][ROWS][COLS];   // 8*18*68*4 = 38.25 KB -> 4 blocks/CU

    const int tid    = threadIdx.x;
    const int n      = blockIdx.z;
    const int x_base = blockIdx.y * TX;
    const int y_base = blockIdx.x * TY;

    // ---- Stage all 8 Cin tiles: float4 global loads -> LDS ----
    const float* __restrict__ inp_n = inp + ((size_t)n * CIN * H * W);
    for (int idx = tid; idx < CIN * ROWS * NCHK; idx += NTHREADS) {
        int c   = idx / (ROWS * NCHK);
        int rem = idx - c * (ROWS * NCHK);
        int r   = rem / NCHK;
        int col = (rem - r * NCHK) * 4;

        int gr = x_base + r - 1;                 // -1 .. 1024
        gr = (gr < 0) ? (H - 1) : ((gr > H - 1) ? (H - 1) : gr);  // -1 wraps (roll); 1024 clamps (dead)
        int gc = y_base + col;
        if (gc > W - 4) gc = W - 4;              // clamped chunks only feed guarded outputs

        const float4 v = *(const float4*)(inp_n + (((size_t)c << 10) + gr) * W + gc);
        *(float4*)&s_in[c][r][col] = v;
    }
    __syncthreads();

    // ---- Compute: thread = (ty, tg): col y_base+ty, rows x_base + tg*2 + {0,1}, all 8 couts ----
    const int ty = tid & 63;
    const int tg = tid >> 6;       // 0..7
    const int r0 = tg * RPT;       // local input row base (tile row 0 == global row x_base-1)

    float acc[RPT][COUT];
#pragma unroll
    for (int o = 0; o < COUT; ++o) {
        const float bv = bias[o];                 // uniform -> s_load
#pragma unroll
        for (int u = 0; u < RPT; ++u) acc[u][o] = bv;
    }

#pragma unroll 1
    for (int c = 0; c < CIN; ++c) {
        float in[RPT + 2][3];
#pragma unroll
        for (int r = 0; r < RPT + 2; ++r)
#pragma unroll
            for (int j = 0; j < 3; ++j)
                in[r][j] = s_in[c][r0 + r][ty + j];

#pragma unroll
        for (int i = 0; i < 3; ++i)
#pragma unroll
            for (int j = 0; j < 3; ++j)
#pragma unroll
                for (int o = 0; o < COUT; ++o) {
                    const float fv = filt[((o * CIN + c) * 3 + i) * 3 + j];  // uniform -> s_load
#pragma unroll
                    for (int u = 0; u < RPT; ++u)
                        acc[u][o] += in[u + i][j] * fv;
                }
    }

    // ---- Store ----
    const int yc = y_base + ty;
    if (yc < OW) {
#pragma unroll
        for (int u = 0; u < RPT; ++u) {
            const int xr = x_base + r0 + u;
            if (xr < OH) {
#pragma unroll
                for (int o = 0; o < COUT; ++o) {
                    out[(((size_t)(n * COUT + o)) * OH + xr) * OW + yc] = acc[u][o];
                }
            }
        }
    }
}

extern "C" void kernel_launch(void* const* d_in, const int* in_sizes, int n_in,
                              void* d_out, int out_size, void* d_ws, size_t ws_size,
                              hipStream_t stream) {
    const float* inp  = (const float*)d_in[0];
    const float* filt = (const float*)d_in[1];
    const float* bias = (const float*)d_in[2];
    float* out = (float*)d_out;

    dim3 grid((OW + TY - 1) / TY,   // 16 y-tiles
              (OH + TX - 1) / TX,   // 64 x-tiles
              8);                   // batch
    conv_roll_kernel<<<grid, dim3(NTHREADS), 0, stream>>>(inp, filt, bias, out);
}